// Round 1
// baseline (1391.798 us; speedup 1.0000x reference)
//
#include <hip/hip_runtime.h>
#include <hip/hip_bf16.h>
#include <math.h>

#define Bsz 2
#define Tseq 2048
#define Cdim 1024
#define Hn 16
#define HDim 64
#define Mrows (Bsz*Tseq)   // 4096
#define N3 (3*Cdim)        // 3072

// ---------------------------------------------------------------------------
// Kernel 1: qkv = x @ w_attn + b_attn, rotary on q/k, scatter to (B,H,T,HD)
// 64x64 output tile per block, 256 threads, each thread 4x4 micro-tile, fp32.
// ---------------------------------------------------------------------------
__global__ __launch_bounds__(256) void qkv_kernel(
    const float* __restrict__ x, const float* __restrict__ w,
    const float* __restrict__ bias, const float* __restrict__ cosb,
    const float* __restrict__ sinb, float* __restrict__ qb,
    float* __restrict__ kb, float* __restrict__ vb)
{
    __shared__ float As[64][16];
    __shared__ float Bs[16][64];
    const int tid = threadIdx.x;
    const int tx = tid & 15, ty = tid >> 4;
    const int m0 = blockIdx.y << 6;
    const int n0 = blockIdx.x << 6;

    float acc[4][4] = {};

    const int arow = tid >> 2, akv = (tid & 3) << 2;
    const int brow = tid >> 4, bnv = (tid & 15) << 2;

    for (int k0 = 0; k0 < Cdim; k0 += 16) {
        *(float4*)&As[arow][akv] =
            *(const float4*)(x + (size_t)(m0 + arow) * Cdim + k0 + akv);
        *(float4*)&Bs[brow][bnv] =
            *(const float4*)(w + (size_t)(k0 + brow) * N3 + n0 + bnv);
        __syncthreads();
        #pragma unroll
        for (int kk = 0; kk < 16; ++kk) {
            float av[4];
            #pragma unroll
            for (int i = 0; i < 4; ++i) av[i] = As[(ty << 2) + i][kk];
            float4 b4 = *(const float4*)&Bs[kk][tx << 2];
            float bv[4] = {b4.x, b4.y, b4.z, b4.w};
            #pragma unroll
            for (int i = 0; i < 4; ++i)
                #pragma unroll
                for (int j = 0; j < 4; ++j)
                    acc[i][j] += av[i] * bv[j];
        }
        __syncthreads();
    }

    // epilogue: bias + rotary (q,k) + scatter. Tile spans exactly one head.
    const int sec = n0 >> 10;            // 0=q 1=k 2=v
    const int csec = n0 & 1023;
    const int h = csec >> 6;
    const int d = tx << 2;               // within-head dim offset (even)
    float* dst = (sec == 0) ? qb : ((sec == 1) ? kb : vb);

    const float bi0 = bias[n0 + d + 0];
    const float bi1 = bias[n0 + d + 1];
    const float bi2 = bias[n0 + d + 2];
    const float bi3 = bias[n0 + d + 3];

    #pragma unroll
    for (int i = 0; i < 4; ++i) {
        int m = m0 + (ty << 2) + i;
        int b = m >> 11, t = m & 2047;
        float e0 = acc[i][0] + bi0;
        float o0 = acc[i][1] + bi1;
        float e1 = acc[i][2] + bi2;
        float o1 = acc[i][3] + bi3;
        if (sec < 2) {
            float c0 = cosb[t * (HDim / 2) + (d >> 1)];
            float s0 = sinb[t * (HDim / 2) + (d >> 1)];
            float c1 = cosb[t * (HDim / 2) + ((d + 2) >> 1)];
            float s1 = sinb[t * (HDim / 2) + ((d + 2) >> 1)];
            float r;
            r = e0 * c0 - o0 * s0; o0 = e0 * s0 + o0 * c0; e0 = r;
            r = e1 * c1 - o1 * s1; o1 = e1 * s1 + o1 * c1; e1 = r;
        }
        float4 outv = make_float4(e0, o0, e1, o1);
        *(float4*)(dst + (((size_t)(b * Hn + h) * Tseq + t) * HDim + d)) = outv;
    }
}

// ---------------------------------------------------------------------------
// Kernel 2: flash attention, fp32. One block per (b,h,q-tile of 64 rows).
// Online softmax; K/V 64x64 tiles in LDS (pitch 65 to break bank conflicts).
// Writes y in (B,T,C) layout for the proj GEMM.
// ---------------------------------------------------------------------------
__global__ __launch_bounds__(256) void attn_kernel(
    const float* __restrict__ qb, const float* __restrict__ kb,
    const float* __restrict__ vb, float* __restrict__ yb)
{
    const int qt = blockIdx.x;           // 0..31
    const int bh = blockIdx.y;           // 0..31
    const int b = bh >> 4, h = bh & 15;

    __shared__ float Qs[64][65];
    __shared__ float Ks[64][65];
    __shared__ float Vs[64][65];
    __shared__ float Ss[64][65];
    __shared__ float mrow[64], lrow[64], arow[64];

    const int tid = threadIdx.x;
    const int tx = tid & 15, ty = tid >> 4;

    const float* qptr = qb + ((size_t)bh * Tseq + (size_t)qt * 64) * HDim;

    #pragma unroll
    for (int r = 0; r < 4; ++r) {
        int idx = tid + (r << 8);
        int row = idx >> 4, col = (idx & 15) << 2;
        float4 v4 = *(const float4*)(qptr + row * HDim + col);
        Qs[row][col + 0] = v4.x; Qs[row][col + 1] = v4.y;
        Qs[row][col + 2] = v4.z; Qs[row][col + 3] = v4.w;
    }
    if (tid < 64) { mrow[tid] = -1e30f; lrow[tid] = 0.f; }

    float acc[4][4] = {};
    const float scale = 0.125f;          // 1/sqrt(64)

    for (int kt = 0; kt <= qt; ++kt) {
        __syncthreads();                 // protect Ks/Vs/Ss reuse
        const float* kptr = kb + ((size_t)bh * Tseq + (size_t)kt * 64) * HDim;
        const float* vptr = vb + ((size_t)bh * Tseq + (size_t)kt * 64) * HDim;
        #pragma unroll
        for (int r = 0; r < 4; ++r) {
            int idx = tid + (r << 8);
            int row = idx >> 4, col = (idx & 15) << 2;
            float4 k4 = *(const float4*)(kptr + row * HDim + col);
            Ks[row][col + 0] = k4.x; Ks[row][col + 1] = k4.y;
            Ks[row][col + 2] = k4.z; Ks[row][col + 3] = k4.w;
            float4 v4 = *(const float4*)(vptr + row * HDim + col);
            Vs[row][col + 0] = v4.x; Vs[row][col + 1] = v4.y;
            Vs[row][col + 2] = v4.z; Vs[row][col + 3] = v4.w;
        }
        __syncthreads();

        // S = scale * Q K^T with causal mask
        float s[4][4] = {};
        for (int dd = 0; dd < 64; ++dd) {
            float qv[4], kv[4];
            #pragma unroll
            for (int i = 0; i < 4; ++i) qv[i] = Qs[(ty << 2) + i][dd];
            #pragma unroll
            for (int j = 0; j < 4; ++j) kv[j] = Ks[(tx << 2) + j][dd];
            #pragma unroll
            for (int i = 0; i < 4; ++i)
                #pragma unroll
                for (int j = 0; j < 4; ++j)
                    s[i][j] += qv[i] * kv[j];
        }
        #pragma unroll
        for (int i = 0; i < 4; ++i) {
            int gi = (qt << 6) + (ty << 2) + i;
            #pragma unroll
            for (int j = 0; j < 4; ++j) {
                int gj = (kt << 6) + (tx << 2) + j;
                float val = (gj > gi) ? -1e30f : s[i][j] * scale;
                Ss[(ty << 2) + i][(tx << 2) + j] = val;
            }
        }
        __syncthreads();

        // online softmax row stats (one thread per row)
        if (tid < 64) {
            float m_old = mrow[tid];
            float mx = m_old;
            for (int j = 0; j < 64; ++j) mx = fmaxf(mx, Ss[tid][j]);
            float al = expf(m_old - mx);
            float sum = 0.f;
            for (int j = 0; j < 64; ++j) {
                float p = expf(Ss[tid][j] - mx);
                Ss[tid][j] = p;
                sum += p;
            }
            mrow[tid] = mx;
            lrow[tid] = lrow[tid] * al + sum;
            arow[tid] = al;
        }
        __syncthreads();

        // O = O*alpha + P @ V
        #pragma unroll
        for (int i = 0; i < 4; ++i) {
            float al = arow[(ty << 2) + i];
            #pragma unroll
            for (int j = 0; j < 4; ++j) acc[i][j] *= al;
        }
        for (int dd = 0; dd < 64; ++dd) {
            float pv[4], vv[4];
            #pragma unroll
            for (int i = 0; i < 4; ++i) pv[i] = Ss[(ty << 2) + i][dd];
            #pragma unroll
            for (int j = 0; j < 4; ++j) vv[j] = Vs[dd][(tx << 2) + j];
            #pragma unroll
            for (int i = 0; i < 4; ++i)
                #pragma unroll
                for (int j = 0; j < 4; ++j)
                    acc[i][j] += pv[i] * vv[j];
        }
    }

    // write out y[b][t][h*64+d]
    #pragma unroll
    for (int i = 0; i < 4; ++i) {
        int row = (ty << 2) + i;
        int t = (qt << 6) + row;
        float inv = 1.f / lrow[row];
        float4 outv = make_float4(acc[i][0] * inv, acc[i][1] * inv,
                                  acc[i][2] * inv, acc[i][3] * inv);
        *(float4*)(yb + ((size_t)(b * Tseq + t) * Cdim) + (h << 6) + (tx << 2)) = outv;
    }
}

// ---------------------------------------------------------------------------
// Kernel 3: out = y @ w_proj + b_proj. Same GEMM structure as kernel 1.
// ---------------------------------------------------------------------------
__global__ __launch_bounds__(256) void proj_kernel(
    const float* __restrict__ y, const float* __restrict__ w,
    const float* __restrict__ bias, float* __restrict__ out)
{
    __shared__ float As[64][16];
    __shared__ float Bs[16][64];
    const int tid = threadIdx.x;
    const int tx = tid & 15, ty = tid >> 4;
    const int m0 = blockIdx.y << 6;
    const int n0 = blockIdx.x << 6;

    float acc[4][4] = {};

    const int arow = tid >> 2, akv = (tid & 3) << 2;
    const int brow = tid >> 4, bnv = (tid & 15) << 2;

    for (int k0 = 0; k0 < Cdim; k0 += 16) {
        *(float4*)&As[arow][akv] =
            *(const float4*)(y + (size_t)(m0 + arow) * Cdim + k0 + akv);
        *(float4*)&Bs[brow][bnv] =
            *(const float4*)(w + (size_t)(k0 + brow) * Cdim + n0 + bnv);
        __syncthreads();
        #pragma unroll
        for (int kk = 0; kk < 16; ++kk) {
            float av[4];
            #pragma unroll
            for (int i = 0; i < 4; ++i) av[i] = As[(ty << 2) + i][kk];
            float4 b4 = *(const float4*)&Bs[kk][tx << 2];
            float bv[4] = {b4.x, b4.y, b4.z, b4.w};
            #pragma unroll
            for (int i = 0; i < 4; ++i)
                #pragma unroll
                for (int j = 0; j < 4; ++j)
                    acc[i][j] += av[i] * bv[j];
        }
        __syncthreads();
    }

    const float bi0 = bias[n0 + (tx << 2) + 0];
    const float bi1 = bias[n0 + (tx << 2) + 1];
    const float bi2 = bias[n0 + (tx << 2) + 2];
    const float bi3 = bias[n0 + (tx << 2) + 3];
    #pragma unroll
    for (int i = 0; i < 4; ++i) {
        int m = m0 + (ty << 2) + i;
        float4 outv = make_float4(acc[i][0] + bi0, acc[i][1] + bi1,
                                  acc[i][2] + bi2, acc[i][3] + bi3);
        *(float4*)(out + (size_t)m * Cdim + n0 + (tx << 2)) = outv;
    }
}

extern "C" void kernel_launch(void* const* d_in, const int* in_sizes, int n_in,
                              void* d_out, int out_size, void* d_ws, size_t ws_size,
                              hipStream_t stream) {
    const float* x      = (const float*)d_in[0];
    const float* cosb   = (const float*)d_in[1];
    const float* sinb   = (const float*)d_in[2];
    const float* w_attn = (const float*)d_in[3];
    const float* b_attn = (const float*)d_in[4];
    const float* w_proj = (const float*)d_in[5];
    const float* b_proj = (const float*)d_in[6];
    float* out = (float*)d_out;

    float* ws = (float*)d_ws;
    float* qb = ws;                       // 4.19M floats each (16 MB)
    float* kb = ws + 4194304;
    float* vb = ws + 8388608;
    float* yb = ws + 12582912;            // total 64 MB

    dim3 blk(256);
    qkv_kernel<<<dim3(N3 / 64, Mrows / 64), blk, 0, stream>>>(
        x, w_attn, b_attn, cosb, sinb, qb, kb, vb);
    attn_kernel<<<dim3(Tseq / 64, Bsz * Hn), blk, 0, stream>>>(qb, kb, vb, yb);
    proj_kernel<<<dim3(Cdim / 64, Mrows / 64), blk, 0, stream>>>(
        yb, w_proj, b_proj, out);
}

// Round 2
// 299.413 us; speedup vs baseline: 4.6484x; 4.6484x over previous
//
#include <hip/hip_runtime.h>
#include <hip/hip_bf16.h>
#include <math.h>

#define Bsz 2
#define Tseq 2048
#define Cdim 1024
#define Hn 16
#define HDim 64
#define Mrows 4096
#define N3 3072

typedef __bf16 bf16_t;
typedef __bf16 bf16x4 __attribute__((ext_vector_type(4)));
typedef __bf16 bf16x8 __attribute__((ext_vector_type(8)));
typedef float floatx4 __attribute__((ext_vector_type(4)));

__device__ __forceinline__ void async16(const void* g, void* l) {
    __builtin_amdgcn_global_load_lds(
        (const __attribute__((address_space(1))) void*)g,
        (__attribute__((address_space(3))) void*)l, 16, 0, 0);
}

// ---------------------------------------------------------------------------
// fp32 -> bf16 convert (x), 8 elems/thread
// ---------------------------------------------------------------------------
__global__ __launch_bounds__(256) void convert_kernel(
    const float* __restrict__ in, bf16_t* __restrict__ out)
{
    size_t g = (size_t)blockIdx.x * 256 + threadIdx.x;
    float4 a = *(const float4*)(in + g * 8);
    float4 b = *(const float4*)(in + g * 8 + 4);
    bf16x8 o;
    o[0] = (bf16_t)a.x; o[1] = (bf16_t)a.y; o[2] = (bf16_t)a.z; o[3] = (bf16_t)a.w;
    o[4] = (bf16_t)b.x; o[5] = (bf16_t)b.y; o[6] = (bf16_t)b.z; o[7] = (bf16_t)b.w;
    *(bf16x8*)(out + g * 8) = o;
}

// ---------------------------------------------------------------------------
// fp32 (R,C) -> bf16 (C,R) transpose-convert, 32x32 tiles
// ---------------------------------------------------------------------------
__global__ __launch_bounds__(256) void transpose_kernel(
    const float* __restrict__ in, bf16_t* __restrict__ out, int R, int C)
{
    __shared__ float Ts[32][33];
    int c0 = blockIdx.x << 5, r0 = blockIdx.y << 5;
    int lr = threadIdx.x >> 3, lc = (threadIdx.x & 7) << 2;
    float4 v = *(const float4*)(in + (size_t)(r0 + lr) * C + c0 + lc);
    Ts[lr][lc] = v.x; Ts[lr][lc + 1] = v.y; Ts[lr][lc + 2] = v.z; Ts[lr][lc + 3] = v.w;
    __syncthreads();
    bf16x4 o;
    o[0] = (bf16_t)Ts[lc + 0][lr]; o[1] = (bf16_t)Ts[lc + 1][lr];
    o[2] = (bf16_t)Ts[lc + 2][lr]; o[3] = (bf16_t)Ts[lc + 3][lr];
    *(bf16x4*)(out + (size_t)(c0 + lr) * R + r0 + lc) = o;
}

// ---------------------------------------------------------------------------
// QKV GEMM: (4096x1024) @ (1024x3072), A=xb (M,K) bf16, B=waT (N,K) bf16.
// m97 structure: 128x128 tile, 4 waves 2x2, 16x16x32 bf16 MFMA, BK=32,
// global_load_lds width 16, XOR-swizzled LDS chunks.
// Epilogue: +bias, scatter q/k to (BH,T,HD), v transposed to (BH,HD,T).
// ---------------------------------------------------------------------------
__global__ __launch_bounds__(256) void gemm_qkv(
    const bf16_t* __restrict__ xb, const bf16_t* __restrict__ waT,
    const float* __restrict__ bias,
    bf16_t* __restrict__ qb, bf16_t* __restrict__ kb, bf16_t* __restrict__ vT)
{
    __shared__ bf16_t As[128 * 32];
    __shared__ bf16_t Bs[128 * 32];
    const int tid = threadIdx.x;
    const int lane = tid & 63, w = tid >> 6;
    const int lm = lane & 15, quad = lane >> 4;
    const int wy = w >> 1, wx = w & 1;
    const int m0 = blockIdx.y << 7, n0 = blockIdx.x << 7;

    const floatx4 fz = {0.f, 0.f, 0.f, 0.f};
    floatx4 acc[4][4];
    #pragma unroll
    for (int i = 0; i < 4; i++)
        #pragma unroll
        for (int j = 0; j < 4; j++) acc[i][j] = fz;

    const bf16_t* Ag = xb + (size_t)m0 * Cdim;
    const bf16_t* Bg = waT + (size_t)n0 * Cdim;

    for (int k0 = 0; k0 < Cdim; k0 += 32) {
        #pragma unroll
        for (int it = 0; it < 2; ++it) {
            int ci = (w << 7) + (it << 6) + lane;
            int row = ci >> 2, cq = (ci & 3) ^ (row & 3);
            async16(Ag + (size_t)row * Cdim + k0 + cq * 8, As + ((w << 7) + (it << 6)) * 8);
            async16(Bg + (size_t)row * Cdim + k0 + cq * 8, Bs + ((w << 7) + (it << 6)) * 8);
        }
        __syncthreads();
        bf16x8 af[4], bfr[4];
        #pragma unroll
        for (int i = 0; i < 4; i++) {
            int row = (wy << 6) + (i << 4) + lm;
            int cq = quad ^ (lm & 3);
            af[i] = *(const bf16x8*)&As[row * 32 + cq * 8];
        }
        #pragma unroll
        for (int j = 0; j < 4; j++) {
            int row = (wx << 6) + (j << 4) + lm;
            int cq = quad ^ (lm & 3);
            bfr[j] = *(const bf16x8*)&Bs[row * 32 + cq * 8];
        }
        #pragma unroll
        for (int i = 0; i < 4; i++)
            #pragma unroll
            for (int j = 0; j < 4; j++)
                acc[i][j] = __builtin_amdgcn_mfma_f32_16x16x32_bf16(af[i], bfr[j], acc[i][j], 0, 0, 0);
        __syncthreads();
    }

    // epilogue: C/D layout col=lane&15, row=quad*4+reg
    const int sec = n0 >> 10;                 // block-uniform: 0=q 1=k 2=v
    const int mb = m0 + (wy << 6);
    const int nb = n0 + (wx << 6);
    #pragma unroll
    for (int i = 0; i < 4; i++) {
        int mrow0 = mb + (i << 4) + (quad << 2);
        int b = mrow0 >> 11, t0 = mrow0 & 2047;
        #pragma unroll
        for (int j = 0; j < 4; j++) {
            int n = nb + (j << 4) + lm;
            float bi = bias[n];
            int rel = n & 1023;
            int h = rel >> 6, hd = rel & 63;
            if (sec == 2) {
                bf16x4 pk;
                #pragma unroll
                for (int r = 0; r < 4; r++) pk[r] = (bf16_t)(acc[i][j][r] + bi);
                *(bf16x4*)&vT[((size_t)(b * Hn + h) * HDim + hd) * Tseq + t0] = pk;
            } else {
                bf16_t* dst = (sec == 0) ? qb : kb;
                #pragma unroll
                for (int r = 0; r < 4; r++)
                    dst[((size_t)(b * Hn + h) * Tseq + t0 + r) * HDim + hd] =
                        (bf16_t)(acc[i][j][r] + bi);
            }
        }
    }
}

// ---------------------------------------------------------------------------
// rotary on q,k in (BH,T,HD) bf16; 4 elems (2 pairs) per thread
// ---------------------------------------------------------------------------
__global__ __launch_bounds__(256) void rotary_kernel(
    bf16_t* __restrict__ qb, bf16_t* __restrict__ kb,
    const float* __restrict__ cosb, const float* __restrict__ sinb)
{
    int g = blockIdx.x * 256 + threadIdx.x;       // 0..2097151
    bf16_t* buf = (g >= 1048576) ? kb : qb;
    int gg = g & 1048575;
    int bh = gg >> 15;
    int t = (gg >> 4) & 2047;
    int goff = (gg & 15) << 2;
    bf16_t* p = buf + ((size_t)bh * Tseq + t) * HDim + goff;
    bf16x4 v = *(bf16x4*)p;
    int ih = goff >> 1;
    float c0 = cosb[t * 32 + ih], s0 = sinb[t * 32 + ih];
    float c1 = cosb[t * 32 + ih + 1], s1 = sinb[t * 32 + ih + 1];
    float e0 = (float)v[0], o0 = (float)v[1], e1 = (float)v[2], o1 = (float)v[3];
    bf16x4 ov;
    ov[0] = (bf16_t)(e0 * c0 - o0 * s0);
    ov[1] = (bf16_t)(e0 * s0 + o0 * c0);
    ov[2] = (bf16_t)(e1 * c1 - o1 * s1);
    ov[3] = (bf16_t)(e1 * s1 + o1 * c1);
    *(bf16x4*)p = ov;
}

// ---------------------------------------------------------------------------
// Flash attention, bf16 MFMA. Block = 128 q-rows of one (b,h); 4 waves x 32
// rows. K/V tiles of 64. Waves own their rows -> softmax via width-16
// shfl_xor only. P goes through padded LDS (pitch 72) to A-operand layout.
// ---------------------------------------------------------------------------
__global__ __launch_bounds__(256) void attn_mfma(
    const bf16_t* __restrict__ qb, const bf16_t* __restrict__ kb,
    const bf16_t* __restrict__ vT, bf16_t* __restrict__ yb)
{
    __shared__ bf16_t Qs[128 * 64];
    __shared__ bf16_t Ks[64 * 64];
    __shared__ bf16_t VTs[64 * 64];
    __shared__ bf16_t Ps[128 * 72];

    const int qt = 15 - blockIdx.x;           // heavy blocks dispatch first
    const int bh = blockIdx.y;
    const int b = bh >> 4, h = bh & 15;
    const int tid = threadIdx.x;
    const int lane = tid & 63, w = tid >> 6;
    const int lm = lane & 15, quad = lane >> 4;

    // stage Q once (swizzled 16B chunks, rows of 8 chunks)
    const bf16_t* Qg = qb + ((size_t)bh * Tseq + (qt << 7)) * HDim;
    #pragma unroll
    for (int it = 0; it < 4; ++it) {
        int ci = (w << 8) + (it << 6) + lane;
        int row = ci >> 3, cq = (ci & 7) ^ (row & 7);
        async16(Qg + row * HDim + cq * 8, Qs + ((w << 8) + (it << 6)) * 8);
    }

    const floatx4 fz = {0.f, 0.f, 0.f, 0.f};
    floatx4 o_[2][4];
    #pragma unroll
    for (int i = 0; i < 2; i++)
        #pragma unroll
        for (int j = 0; j < 4; j++) o_[i][j] = fz;
    float m_[2][4], l_[2][4];
    #pragma unroll
    for (int i = 0; i < 2; i++)
        #pragma unroll
        for (int r = 0; r < 4; r++) { m_[i][r] = -1e30f; l_[i][r] = 0.f; }

    const int kt_end = 2 * qt + 1;
    for (int kt = 0; kt <= kt_end; ++kt) {
        const bf16_t* Kg = kb + ((size_t)bh * Tseq + (kt << 6)) * HDim;
        const bf16_t* Vg = vT + (size_t)bh * HDim * Tseq + (kt << 6);
        #pragma unroll
        for (int it = 0; it < 2; ++it) {
            int ci = (w << 7) + (it << 6) + lane;
            int row = ci >> 3, cq = (ci & 7) ^ (row & 7);
            async16(Kg + row * HDim + cq * 8, Ks + ((w << 7) + (it << 6)) * 8);
            async16(Vg + (size_t)row * Tseq + cq * 8, VTs + ((w << 7) + (it << 6)) * 8);
        }
        __syncthreads();

        bool active = (kt << 6) <= ((qt << 7) + (w << 5) + 31);
        if (active) {
            // S = Q K^T (rows w*32..+31, cols kt*64..+63)
            floatx4 s[2][4];
            #pragma unroll
            for (int i = 0; i < 2; i++)
                #pragma unroll
                for (int j = 0; j < 4; j++) s[i][j] = fz;
            #pragma unroll
            for (int ks = 0; ks < 2; ++ks) {
                bf16x8 aq[2], bk[4];
                #pragma unroll
                for (int i = 0; i < 2; i++) {
                    int row = (w << 5) + (i << 4) + lm;
                    int cq = (ks * 4 + quad) ^ (lm & 7);
                    aq[i] = *(const bf16x8*)&Qs[row * 64 + cq * 8];
                }
                #pragma unroll
                for (int j = 0; j < 4; j++) {
                    int row = (j << 4) + lm;
                    int cq = (ks * 4 + quad) ^ (lm & 7);
                    bk[j] = *(const bf16x8*)&Ks[row * 64 + cq * 8];
                }
                #pragma unroll
                for (int i = 0; i < 2; i++)
                    #pragma unroll
                    for (int j = 0; j < 4; j++)
                        s[i][j] = __builtin_amdgcn_mfma_f32_16x16x32_bf16(aq[i], bk[j], s[i][j], 0, 0, 0);
            }
            // online softmax (rows = quad*4+r, wave-exclusive)
            #pragma unroll
            for (int i = 0; i < 2; i++) {
                #pragma unroll
                for (int r = 0; r < 4; r++) {
                    int gq = (qt << 7) + (w << 5) + (i << 4) + (quad << 2) + r;
                    float sv[4];
                    float rowmax = -1e30f;
                    #pragma unroll
                    for (int j = 0; j < 4; j++) {
                        int gk = (kt << 6) + (j << 4) + lm;
                        float v = s[i][j][r] * 0.125f;
                        v = (gk > gq) ? -1e30f : v;
                        sv[j] = v;
                        rowmax = fmaxf(rowmax, v);
                    }
                    #pragma unroll
                    for (int off = 1; off < 16; off <<= 1)
                        rowmax = fmaxf(rowmax, __shfl_xor(rowmax, off));
                    float mold = m_[i][r];
                    float mnew = fmaxf(mold, rowmax);
                    float alpha = exp2f((mold - mnew) * 1.44269504f);
                    float rs = 0.f;
                    #pragma unroll
                    for (int j = 0; j < 4; j++) {
                        float p = exp2f((sv[j] - mnew) * 1.44269504f);
                        sv[j] = p;
                        rs += p;
                    }
                    #pragma unroll
                    for (int off = 1; off < 16; off <<= 1)
                        rs += __shfl_xor(rs, off);
                    m_[i][r] = mnew;
                    l_[i][r] = l_[i][r] * alpha + rs;
                    #pragma unroll
                    for (int jo = 0; jo < 4; jo++) o_[i][jo][r] *= alpha;
                    int prow = (w << 5) + (i << 4) + (quad << 2) + r;
                    #pragma unroll
                    for (int j = 0; j < 4; j++)
                        Ps[prow * 72 + (j << 4) + lm] = (bf16_t)sv[j];
                }
            }
            // O += P V   (A from Ps, B from VTs[n=hd][k=key])
            #pragma unroll
            for (int ks = 0; ks < 2; ++ks) {
                bf16x8 ap[2], bv[4];
                #pragma unroll
                for (int i = 0; i < 2; i++)
                    ap[i] = *(const bf16x8*)&Ps[((w << 5) + (i << 4) + lm) * 72 + (ks << 5) + (quad << 3)];
                #pragma unroll
                for (int j = 0; j < 4; j++) {
                    int row = (j << 4) + lm;
                    int cq = (ks * 4 + quad) ^ (lm & 7);
                    bv[j] = *(const bf16x8*)&VTs[row * 64 + cq * 8];
                }
                #pragma unroll
                for (int i = 0; i < 2; i++)
                    #pragma unroll
                    for (int j = 0; j < 4; j++)
                        o_[i][j] = __builtin_amdgcn_mfma_f32_16x16x32_bf16(ap[i], bv[j], o_[i][j], 0, 0, 0);
            }
        }
        __syncthreads();
    }

    // epilogue: y[b][t][h*64+hd] bf16
    #pragma unroll
    for (int i = 0; i < 2; i++) {
        #pragma unroll
        for (int r = 0; r < 4; r++) {
            int t = (qt << 7) + (w << 5) + (i << 4) + (quad << 2) + r;
            float inv = 1.f / l_[i][r];
            #pragma unroll
            for (int j = 0; j < 4; j++) {
                int hd = (j << 4) + lm;
                yb[(size_t)(b * Tseq + t) * Cdim + (h << 6) + hd] =
                    (bf16_t)(o_[i][j][r] * inv);
            }
        }
    }
}

// ---------------------------------------------------------------------------
// Proj GEMM: (4096x1024) @ (1024x1024) + bias -> fp32 out. Same structure.
// ---------------------------------------------------------------------------
__global__ __launch_bounds__(256) void gemm_proj(
    const bf16_t* __restrict__ yb, const bf16_t* __restrict__ wpT,
    const float* __restrict__ bias, float* __restrict__ out)
{
    __shared__ bf16_t As[128 * 32];
    __shared__ bf16_t Bs[128 * 32];
    const int tid = threadIdx.x;
    const int lane = tid & 63, w = tid >> 6;
    const int lm = lane & 15, quad = lane >> 4;
    const int wy = w >> 1, wx = w & 1;
    const int m0 = blockIdx.y << 7, n0 = blockIdx.x << 7;

    const floatx4 fz = {0.f, 0.f, 0.f, 0.f};
    floatx4 acc[4][4];
    #pragma unroll
    for (int i = 0; i < 4; i++)
        #pragma unroll
        for (int j = 0; j < 4; j++) acc[i][j] = fz;

    const bf16_t* Ag = yb + (size_t)m0 * Cdim;
    const bf16_t* Bg = wpT + (size_t)n0 * Cdim;

    for (int k0 = 0; k0 < Cdim; k0 += 32) {
        #pragma unroll
        for (int it = 0; it < 2; ++it) {
            int ci = (w << 7) + (it << 6) + lane;
            int row = ci >> 2, cq = (ci & 3) ^ (row & 3);
            async16(Ag + (size_t)row * Cdim + k0 + cq * 8, As + ((w << 7) + (it << 6)) * 8);
            async16(Bg + (size_t)row * Cdim + k0 + cq * 8, Bs + ((w << 7) + (it << 6)) * 8);
        }
        __syncthreads();
        bf16x8 af[4], bfr[4];
        #pragma unroll
        for (int i = 0; i < 4; i++) {
            int row = (wy << 6) + (i << 4) + lm;
            int cq = quad ^ (lm & 3);
            af[i] = *(const bf16x8*)&As[row * 32 + cq * 8];
        }
        #pragma unroll
        for (int j = 0; j < 4; j++) {
            int row = (wx << 6) + (j << 4) + lm;
            int cq = quad ^ (lm & 3);
            bfr[j] = *(const bf16x8*)&Bs[row * 32 + cq * 8];
        }
        #pragma unroll
        for (int i = 0; i < 4; i++)
            #pragma unroll
            for (int j = 0; j < 4; j++)
                acc[i][j] = __builtin_amdgcn_mfma_f32_16x16x32_bf16(af[i], bfr[j], acc[i][j], 0, 0, 0);
        __syncthreads();
    }

    const int mb = m0 + (wy << 6);
    const int nb = n0 + (wx << 6);
    #pragma unroll
    for (int i = 0; i < 4; i++) {
        int mrow0 = mb + (i << 4) + (quad << 2);
        #pragma unroll
        for (int j = 0; j < 4; j++) {
            int n = nb + (j << 4) + lm;
            float bi = bias[n];
            #pragma unroll
            for (int r = 0; r < 4; r++)
                out[(size_t)(mrow0 + r) * Cdim + n] = acc[i][j][r] + bi;
        }
    }
}

extern "C" void kernel_launch(void* const* d_in, const int* in_sizes, int n_in,
                              void* d_out, int out_size, void* d_ws, size_t ws_size,
                              hipStream_t stream) {
    const float* x      = (const float*)d_in[0];
    const float* cosb   = (const float*)d_in[1];
    const float* sinb   = (const float*)d_in[2];
    const float* w_attn = (const float*)d_in[3];
    const float* b_attn = (const float*)d_in[4];
    const float* w_proj = (const float*)d_in[5];
    const float* b_proj = (const float*)d_in[6];

    char* ws = (char*)d_ws;
    bf16_t* xb  = (bf16_t*)(ws);                       //  8 MB: x bf16 (M,K)
    bf16_t* waT = (bf16_t*)(ws + (size_t)(8 << 20));   //  6 MB: w_attn^T (N,K)
    bf16_t* wpT = (bf16_t*)(ws + (size_t)(14 << 20));  //  2 MB: w_proj^T (N,K)
    bf16_t* qb  = (bf16_t*)(ws + (size_t)(16 << 20));  //  8 MB: q (BH,T,HD)
    bf16_t* kb  = (bf16_t*)(ws + (size_t)(24 << 20));  //  8 MB: k (BH,T,HD)
    bf16_t* vT  = (bf16_t*)(ws + (size_t)(32 << 20));  //  8 MB: v^T (BH,HD,T)
    bf16_t* yb  = (bf16_t*)(ws + (size_t)(40 << 20));  //  8 MB: attn out (M,C)

    convert_kernel<<<2048, 256, 0, stream>>>(x, xb);
    transpose_kernel<<<dim3(96, 32), 256, 0, stream>>>(w_attn, waT, Cdim, N3);
    transpose_kernel<<<dim3(32, 32), 256, 0, stream>>>(w_proj, wpT, Cdim, Cdim);
    gemm_qkv<<<dim3(24, 32), 256, 0, stream>>>(xb, waT, b_attn, qb, kb, vT);
    rotary_kernel<<<8192, 256, 0, stream>>>(qb, kb, cosb, sinb);
    attn_mfma<<<dim3(16, 32), 256, 0, stream>>>(qb, kb, vT, yb);
    gemm_proj<<<dim3(8, 32), 256, 0, stream>>>(yb, wpT, b_proj, (float*)d_out);
}

// Round 3
// 220.714 us; speedup vs baseline: 6.3059x; 1.3566x over previous
//
#include <hip/hip_runtime.h>
#include <hip/hip_bf16.h>
#include <math.h>

#define Bsz 2
#define Tseq 2048
#define Cdim 1024
#define Hn 16
#define HDim 64
#define Mrows 4096
#define N3 3072
#define QSCALE 0.1803368801111137f   /* 0.125 * log2(e) baked into Q */

typedef __bf16 bf16_t;
typedef __bf16 bf16x4 __attribute__((ext_vector_type(4)));
typedef __bf16 bf16x8 __attribute__((ext_vector_type(8)));
typedef _Float16 f16x4 __attribute__((ext_vector_type(4)));
typedef float floatx4 __attribute__((ext_vector_type(4)));

__device__ __forceinline__ void async16(const void* g, void* l) {
    __builtin_amdgcn_global_load_lds(
        (const __attribute__((address_space(1))) void*)g,
        (__attribute__((address_space(3))) void*)l, 16, 0, 0);
}

// ---------------------------------------------------------------------------
// fp32 -> bf16 convert (x), 8 elems/thread
// ---------------------------------------------------------------------------
__global__ __launch_bounds__(256) void convert_kernel(
    const float* __restrict__ in, bf16_t* __restrict__ out)
{
    size_t g = (size_t)blockIdx.x * 256 + threadIdx.x;
    float4 a = *(const float4*)(in + g * 8);
    float4 b = *(const float4*)(in + g * 8 + 4);
    bf16x8 o;
    o[0] = (bf16_t)a.x; o[1] = (bf16_t)a.y; o[2] = (bf16_t)a.z; o[3] = (bf16_t)a.w;
    o[4] = (bf16_t)b.x; o[5] = (bf16_t)b.y; o[6] = (bf16_t)b.z; o[7] = (bf16_t)b.w;
    *(bf16x8*)(out + g * 8) = o;
}

// ---------------------------------------------------------------------------
// fp32 (R,C) -> bf16 (C,R) transpose-convert, 32x32 tiles
// ---------------------------------------------------------------------------
__global__ __launch_bounds__(256) void transpose_kernel(
    const float* __restrict__ in, bf16_t* __restrict__ out, int R, int C)
{
    __shared__ float Ts[32][33];
    int c0 = blockIdx.x << 5, r0 = blockIdx.y << 5;
    int lr = threadIdx.x >> 3, lc = (threadIdx.x & 7) << 2;
    float4 v = *(const float4*)(in + (size_t)(r0 + lr) * C + c0 + lc);
    Ts[lr][lc] = v.x; Ts[lr][lc + 1] = v.y; Ts[lr][lc + 2] = v.z; Ts[lr][lc + 3] = v.w;
    __syncthreads();
    bf16x4 o;
    o[0] = (bf16_t)Ts[lc + 0][lr]; o[1] = (bf16_t)Ts[lc + 1][lr];
    o[2] = (bf16_t)Ts[lc + 2][lr]; o[3] = (bf16_t)Ts[lc + 3][lr];
    *(bf16x4*)(out + (size_t)(c0 + lr) * R + r0 + lc) = o;
}

// ---------------------------------------------------------------------------
// QKV GEMM (m97 structure) + fused bias + rotary(q,k) + Q pre-scale.
// q,k -> bf16 (BH,T,HD); v -> f16 (BH,HD,T) for the f16 PV MFMA.
// ---------------------------------------------------------------------------
__global__ __launch_bounds__(256) void gemm_qkv(
    const bf16_t* __restrict__ xb, const bf16_t* __restrict__ waT,
    const float* __restrict__ bias, const float* __restrict__ cosb,
    const float* __restrict__ sinb,
    bf16_t* __restrict__ qb, bf16_t* __restrict__ kb, _Float16* __restrict__ vt)
{
    __shared__ bf16_t As[128 * 32];
    __shared__ bf16_t Bs[128 * 32];
    const int tid = threadIdx.x;
    const int lane = tid & 63, w = tid >> 6;
    const int lm = lane & 15, quad = lane >> 4;
    const int wy = w >> 1, wx = w & 1;
    const int m0 = blockIdx.y << 7, n0 = blockIdx.x << 7;

    const floatx4 fz = {0.f, 0.f, 0.f, 0.f};
    floatx4 acc[4][4];
    #pragma unroll
    for (int i = 0; i < 4; i++)
        #pragma unroll
        for (int j = 0; j < 4; j++) acc[i][j] = fz;

    const bf16_t* Ag = xb + (size_t)m0 * Cdim;
    const bf16_t* Bg = waT + (size_t)n0 * Cdim;

    for (int k0 = 0; k0 < Cdim; k0 += 32) {
        #pragma unroll
        for (int it = 0; it < 2; ++it) {
            int ci = (w << 7) + (it << 6) + lane;
            int row = ci >> 2, cq = (ci & 3) ^ (row & 3);
            async16(Ag + (size_t)row * Cdim + k0 + cq * 8, As + ((w << 7) + (it << 6)) * 8);
            async16(Bg + (size_t)row * Cdim + k0 + cq * 8, Bs + ((w << 7) + (it << 6)) * 8);
        }
        __syncthreads();
        bf16x8 af[4], bfr[4];
        #pragma unroll
        for (int i = 0; i < 4; i++) {
            int row = (wy << 6) + (i << 4) + lm;
            int cq = quad ^ (lm & 3);
            af[i] = *(const bf16x8*)&As[row * 32 + cq * 8];
        }
        #pragma unroll
        for (int j = 0; j < 4; j++) {
            int row = (wx << 6) + (j << 4) + lm;
            int cq = quad ^ (lm & 3);
            bfr[j] = *(const bf16x8*)&Bs[row * 32 + cq * 8];
        }
        #pragma unroll
        for (int i = 0; i < 4; i++)
            #pragma unroll
            for (int j = 0; j < 4; j++)
                acc[i][j] = __builtin_amdgcn_mfma_f32_16x16x32_bf16(af[i], bfr[j], acc[i][j], 0, 0, 0);
        __syncthreads();
    }

    // epilogue: C/D layout col=lane&15, row=quad*4+reg
    const int sec = n0 >> 10;                 // block-uniform: 0=q 1=k 2=v
    const int mb = m0 + (wy << 6);
    const int nb = n0 + (wx << 6);
    #pragma unroll
    for (int i = 0; i < 4; i++) {
        int mrow0 = mb + (i << 4) + (quad << 2);
        int b = mrow0 >> 11, t0 = mrow0 & 2047;
        #pragma unroll
        for (int j = 0; j < 4; j++) {
            int n = nb + (j << 4) + lm;
            float bi = bias[n];
            int rel = n & 1023;
            int h = rel >> 6, hd = rel & 63;
            if (sec == 2) {
                f16x4 pk;
                #pragma unroll
                for (int r = 0; r < 4; r++) pk[r] = (_Float16)(acc[i][j][r] + bi);
                *(f16x4*)&vt[((size_t)(b * Hn + h) * HDim + hd) * Tseq + t0] = pk;
            } else {
                bf16_t* dst = (sec == 0) ? qb : kb;
                const int ih = hd >> 1;
                const bool ev = !(hd & 1);
                #pragma unroll
                for (int r = 0; r < 4; r++) {
                    int t = t0 + r;
                    float v = acc[i][j][r] + bi;
                    float x = __shfl_xor(v, 1);        // rotary pair partner
                    float c = cosb[t * 32 + ih], s = sinb[t * 32 + ih];
                    float rv = ev ? (v * c - x * s) : (x * s + v * c);
                    if (sec == 0) rv *= QSCALE;
                    dst[((size_t)(b * Hn + h) * Tseq + t) * HDim + hd] = (bf16_t)rv;
                }
            }
        }
    }
}

// ---------------------------------------------------------------------------
// Flash attention. 256 blocks x 512 threads. Block = (bh, pair p): waves 0-3
// handle q-tile p (128 rows), waves 4-7 q-tile 15-p -> exactly 34 active
// units per block. Shared double-buffered K/V staging, 1 barrier per k-tile.
// S^T = K*Q^T via bf16 x32 MFMA (per-lane softmax: 2 shuffles). P^T C-layout
// feeds v_mfma_f32_16x16x16_f16 B-operand directly (no LDS round trip).
// O^T accumulated; epilogue writes y (B,T,C) bf16.
// ---------------------------------------------------------------------------
__global__ __launch_bounds__(512) void attn_mfma(
    const bf16_t* __restrict__ qb, const bf16_t* __restrict__ kb,
    const _Float16* __restrict__ vt, bf16_t* __restrict__ yb)
{
    __shared__ bf16_t Qs[2][128 * 64];      // 32 KB (one tile per half)
    __shared__ bf16_t Ks[2][64 * 64];       // 16 KB dbuf
    __shared__ _Float16 VTs[2][64 * 64];    // 16 KB dbuf

    const int p = blockIdx.x & 7;
    const int bh = blockIdx.x >> 3;
    const int b = bh >> 4, h = bh & 15;
    const int tid = threadIdx.x;
    const int w8 = tid >> 6;                 // 0..7
    const int half = w8 >> 2, wl = w8 & 3;
    const int lane = tid & 63, lm = lane & 15, quad = lane >> 4;
    const int qt = half ? (15 - p) : p;      // this half's q-tile
    const int kmax = 31 - 2 * p;             // heavy half's last k-tile

    // stage this half's Q tile (16 KB, 4 async16/thread)
    {
        const bf16_t* Qg = qb + ((size_t)bh * Tseq + (qt << 7)) * HDim;
        #pragma unroll
        for (int it = 0; it < 4; ++it) {
            int ci = (wl << 8) + (it << 6) + lane;
            int row = ci >> 3, cq = (ci & 7) ^ (row & 7);
            async16(Qg + row * HDim + cq * 8, &Qs[half][((wl << 8) + (it << 6)) * 8]);
        }
    }
    // stage K/V tile 0 into buf 0 (1+1 async16/thread)
    {
        int ci = tid, row = ci >> 3, cq = (ci & 7) ^ (row & 7);
        async16(kb + ((size_t)bh * Tseq) * HDim + (size_t)row * HDim + cq * 8,
                &Ks[0][(w8 << 6) * 8]);
        async16(vt + (size_t)bh * HDim * Tseq + (size_t)row * Tseq + cq * 8,
                &VTs[0][(w8 << 6) * 8]);
    }
    __syncthreads();

    // loop-invariant Q fragments (B-operand of x32: n=lm, k=quad*8+j)
    bf16x8 qf[2][2];
    #pragma unroll
    for (int i = 0; i < 2; ++i)
        #pragma unroll
        for (int ks = 0; ks < 2; ++ks) {
            int qrow = (wl << 5) + (i << 4) + lm;
            int qc = ((ks << 2) + quad) ^ (qrow & 7);
            qf[i][ks] = *(const bf16x8*)&Qs[half][qrow * 64 + qc * 8];
        }

    const floatx4 fz = {0.f, 0.f, 0.f, 0.f};
    floatx4 o_[4][2];                        // O^T: [d-subtile][q-group]
    #pragma unroll
    for (int f = 0; f < 4; f++)
        #pragma unroll
        for (int i = 0; i < 2; i++) o_[f][i] = fz;
    float m_[2] = {-3e38f, -3e38f}, l_[2] = {0.f, 0.f};

    for (int kt = 0; kt <= kmax; ++kt) {
        const int cb = kt & 1;
        if (kt < kmax) {                      // prefetch next K/V tile
            int nb_ = (kt + 1) & 1;
            int ci = tid, row = ci >> 3, cq = (ci & 7) ^ (row & 7);
            async16(kb + ((size_t)bh * Tseq + ((kt + 1) << 6)) * HDim + (size_t)row * HDim + cq * 8,
                    &Ks[nb_][(w8 << 6) * 8]);
            async16(vt + (size_t)bh * HDim * Tseq + (size_t)row * Tseq + ((kt + 1) << 6) + cq * 8,
                    &VTs[nb_][(w8 << 6) * 8]);
        }

        const bool act = (2 * kt <= 4 * qt + wl);
        if (act) {
            // S^T = K Q^T : m=key (4 subtiles), n=query (2 groups of 16)
            floatx4 st[4][2];
            #pragma unroll
            for (int sub = 0; sub < 4; ++sub)
                #pragma unroll
                for (int i = 0; i < 2; ++i) st[sub][i] = fz;
            #pragma unroll
            for (int ks = 0; ks < 2; ++ks) {
                bf16x8 kf[4];
                #pragma unroll
                for (int sub = 0; sub < 4; ++sub) {
                    int krow = (sub << 4) + lm;
                    int kc = ((ks << 2) + quad) ^ (krow & 7);
                    kf[sub] = *(const bf16x8*)&Ks[cb][krow * 64 + kc * 8];
                }
                #pragma unroll
                for (int sub = 0; sub < 4; ++sub)
                    #pragma unroll
                    for (int i = 0; i < 2; ++i)
                        st[sub][i] = __builtin_amdgcn_mfma_f32_16x16x32_bf16(
                            kf[sub], qf[i][ks], st[sub][i], 0, 0, 0);
            }
            const bool domask = (kt >= 2 * qt);
            f16x4 pf[2][4];
            #pragma unroll
            for (int i = 0; i < 2; ++i) {
                int qg = (qt << 7) + (wl << 5) + (i << 4) + lm;
                float mx = -3e38f;
                float vv[4][4];
                #pragma unroll
                for (int sub = 0; sub < 4; ++sub)
                    #pragma unroll
                    for (int r = 0; r < 4; ++r) {
                        float val = st[sub][i][r];
                        if (domask) {
                            int key = (kt << 6) + (sub << 4) + (quad << 2) + r;
                            val = (key > qg) ? -3e38f : val;
                        }
                        vv[sub][r] = val;
                        mx = fmaxf(mx, val);
                    }
                mx = fmaxf(mx, __shfl_xor(mx, 16));
                mx = fmaxf(mx, __shfl_xor(mx, 32));
                float mnew = fmaxf(m_[i], mx);
                float alpha = exp2f(m_[i] - mnew);
                float rs = 0.f;
                #pragma unroll
                for (int sub = 0; sub < 4; ++sub)
                    #pragma unroll
                    for (int r = 0; r < 4; ++r) {
                        float pp = exp2f(vv[sub][r] - mnew);
                        rs += pp;
                        pf[i][sub][r] = (_Float16)pp;
                    }
                rs += __shfl_xor(rs, 16);
                rs += __shfl_xor(rs, 32);
                m_[i] = mnew;
                l_[i] = l_[i] * alpha + rs;
                #pragma unroll
                for (int f = 0; f < 4; ++f)
                    #pragma unroll
                    for (int r = 0; r < 4; ++r) o_[f][i][r] *= alpha;
            }
            // O^T += V^T P^T  (A = V^T frag, B = P^T straight from regs)
            #pragma unroll
            for (int c = 0; c < 4; ++c) {
                f16x4 vf[4];
                #pragma unroll
                for (int f = 0; f < 4; ++f) {
                    int vrow = (f << 4) + lm;
                    int cc = ((c << 1) + (quad >> 1)) ^ (vrow & 7);
                    vf[f] = *(const f16x4*)&VTs[cb][vrow * 64 + cc * 8 + ((quad & 1) << 2)];
                }
                #pragma unroll
                for (int f = 0; f < 4; ++f)
                    #pragma unroll
                    for (int i = 0; i < 2; ++i)
                        o_[f][i] = __builtin_amdgcn_mfma_f32_16x16x16f16(
                            vf[f], pf[i][c], o_[f][i], 0, 0, 0);
            }
        }
        __syncthreads();
    }

    // epilogue: O^T lane holds query q=lm(+group), d = f*16+quad*4+r
    #pragma unroll
    for (int i = 0; i < 2; ++i) {
        float inv = 1.f / l_[i];
        int q = (qt << 7) + (wl << 5) + (i << 4) + lm;
        size_t base = ((size_t)(b * Tseq) + q) * Cdim + (h << 6) + (quad << 2);
        #pragma unroll
        for (int f = 0; f < 4; ++f) {
            bf16x4 ov;
            #pragma unroll
            for (int r = 0; r < 4; ++r) ov[r] = (bf16_t)(o_[f][i][r] * inv);
            *(bf16x4*)&yb[base + (f << 4)] = ov;
        }
    }
}

// ---------------------------------------------------------------------------
// Proj GEMM: (4096x1024) @ (1024x1024) + bias -> fp32 out.
// ---------------------------------------------------------------------------
__global__ __launch_bounds__(256) void gemm_proj(
    const bf16_t* __restrict__ yb, const bf16_t* __restrict__ wpT,
    const float* __restrict__ bias, float* __restrict__ out)
{
    __shared__ bf16_t As[128 * 32];
    __shared__ bf16_t Bs[128 * 32];
    const int tid = threadIdx.x;
    const int lane = tid & 63, w = tid >> 6;
    const int lm = lane & 15, quad = lane >> 4;
    const int wy = w >> 1, wx = w & 1;
    const int m0 = blockIdx.y << 7, n0 = blockIdx.x << 7;

    const floatx4 fz = {0.f, 0.f, 0.f, 0.f};
    floatx4 acc[4][4];
    #pragma unroll
    for (int i = 0; i < 4; i++)
        #pragma unroll
        for (int j = 0; j < 4; j++) acc[i][j] = fz;

    const bf16_t* Ag = yb + (size_t)m0 * Cdim;
    const bf16_t* Bg = wpT + (size_t)n0 * Cdim;

    for (int k0 = 0; k0 < Cdim; k0 += 32) {
        #pragma unroll
        for (int it = 0; it < 2; ++it) {
            int ci = (w << 7) + (it << 6) + lane;
            int row = ci >> 2, cq = (ci & 3) ^ (row & 3);
            async16(Ag + (size_t)row * Cdim + k0 + cq * 8, As + ((w << 7) + (it << 6)) * 8);
            async16(Bg + (size_t)row * Cdim + k0 + cq * 8, Bs + ((w << 7) + (it << 6)) * 8);
        }
        __syncthreads();
        bf16x8 af[4], bfr[4];
        #pragma unroll
        for (int i = 0; i < 4; i++) {
            int row = (wy << 6) + (i << 4) + lm;
            int cq = quad ^ (lm & 3);
            af[i] = *(const bf16x8*)&As[row * 32 + cq * 8];
        }
        #pragma unroll
        for (int j = 0; j < 4; j++) {
            int row = (wx << 6) + (j << 4) + lm;
            int cq = quad ^ (lm & 3);
            bfr[j] = *(const bf16x8*)&Bs[row * 32 + cq * 8];
        }
        #pragma unroll
        for (int i = 0; i < 4; i++)
            #pragma unroll
            for (int j = 0; j < 4; j++)
                acc[i][j] = __builtin_amdgcn_mfma_f32_16x16x32_bf16(af[i], bfr[j], acc[i][j], 0, 0, 0);
        __syncthreads();
    }

    const int mb = m0 + (wy << 6);
    const int nb = n0 + (wx << 6);
    #pragma unroll
    for (int i = 0; i < 4; i++) {
        int mrow0 = mb + (i << 4) + (quad << 2);
        #pragma unroll
        for (int j = 0; j < 4; j++) {
            int n = nb + (j << 4) + lm;
            float bi = bias[n];
            #pragma unroll
            for (int r = 0; r < 4; r++)
                out[(size_t)(mrow0 + r) * Cdim + n] = acc[i][j][r] + bi;
        }
    }
}

extern "C" void kernel_launch(void* const* d_in, const int* in_sizes, int n_in,
                              void* d_out, int out_size, void* d_ws, size_t ws_size,
                              hipStream_t stream) {
    const float* x      = (const float*)d_in[0];
    const float* cosb   = (const float*)d_in[1];
    const float* sinb   = (const float*)d_in[2];
    const float* w_attn = (const float*)d_in[3];
    const float* b_attn = (const float*)d_in[4];
    const float* w_proj = (const float*)d_in[5];
    const float* b_proj = (const float*)d_in[6];

    char* ws = (char*)d_ws;
    bf16_t*   xb  = (bf16_t*)(ws);                       //  8 MB: x bf16 (M,K)
    bf16_t*   waT = (bf16_t*)(ws + (size_t)(8 << 20));   //  6 MB: w_attn^T (N,K)
    bf16_t*   wpT = (bf16_t*)(ws + (size_t)(14 << 20));  //  2 MB: w_proj^T (N,K)
    bf16_t*   qb  = (bf16_t*)(ws + (size_t)(16 << 20));  //  8 MB: q bf16 (BH,T,HD), pre-scaled
    bf16_t*   kb  = (bf16_t*)(ws + (size_t)(24 << 20));  //  8 MB: k bf16 (BH,T,HD)
    _Float16* vtF = (_Float16*)(ws + (size_t)(32 << 20));//  8 MB: v^T f16 (BH,HD,T)
    bf16_t*   yb  = (bf16_t*)(ws + (size_t)(40 << 20));  //  8 MB: attn out (M,C)

    convert_kernel<<<2048, 256, 0, stream>>>(x, xb);
    transpose_kernel<<<dim3(96, 32), 256, 0, stream>>>(w_attn, waT, Cdim, N3);
    transpose_kernel<<<dim3(32, 32), 256, 0, stream>>>(w_proj, wpT, Cdim, Cdim);
    gemm_qkv<<<dim3(24, 32), 256, 0, stream>>>(xb, waT, b_attn, cosb, sinb, qb, kb, vtF);
    attn_mfma<<<256, 512, 0, stream>>>(qb, kb, vtF, yb);
    gemm_proj<<<dim3(8, 32), 256, 0, stream>>>(yb, wpT, b_proj, (float*)d_out);
}